// Round 8
// baseline (892.255 us; speedup 1.0000x reference)
//
#include <hip/hip_runtime.h>

#define NODE_DIM 256
#define HIDDEN 64
#define NUM_REL 10
#define NPB 64          // nodes per block (4 threads per node)
#define LPAD 68         // LDS row stride in floats (16B-aligned, ≤2-way conflicts)

#define FMA4(A, S, W) do { \
    (A).x = fmaf((S), (W).x, (A).x); \
    (A).y = fmaf((S), (W).y, (A).y); \
    (A).z = fmaf((S), (W).z, (A).z); \
    (A).w = fmaf((S), (W).w, (A).w); } while (0)

#define ELEM(V, I) ((I) == 0 ? (V).x : (I) == 1 ? (V).y : (I) == 2 ? (V).z : (V).w)

// Node pipeline, np/BLAS rounding order per output element (acc=0, ascending-k
// fmaf chain, bias added AFTER, then relu). 4 threads per node, each owns a
// 16-wide j-slice; h1 and h exchanged through LDS (exact fp32 values, no
// re-rounding). h and A(=h@W3[0:64], no bias) stored to global.
__global__ __launch_bounds__(256, 4) void node_kernel(
    const float* __restrict__ x,
    const float* __restrict__ W1, const float* __restrict__ b1,
    const float* __restrict__ W2, const float* __restrict__ b2,
    const float* __restrict__ W3,
    float* __restrict__ Hout, float* __restrict__ Aout, int N)
{
    __shared__ float h1s[NPB][LPAD];
    __shared__ float hs[NPB][LPAD];

    int tid = threadIdx.x;
    int ln = tid >> 2;          // local node 0..63
    int t  = tid & 3;           // j-slice 0..3
    int n  = blockIdx.x * NPB + ln;
    int nc = (n < N) ? n : (N - 1);   // clamped for safe loads

    // ---- L1: h1[t*16..t*16+16) = relu((x@W1) + b1) slice ----
    float4 a0 = make_float4(0.f, 0.f, 0.f, 0.f);
    float4 a1 = a0, a2 = a0, a3 = a0;

    const float4* xr = (const float4*)(x + (size_t)nc * NODE_DIM);
    const float* W1t = W1 + t * 16;
    #pragma unroll 1
    for (int k4 = 0; k4 < NODE_DIM / 4; ++k4) {
        float4 xv = xr[k4];
        #pragma unroll
        for (int i = 0; i < 4; ++i) {
            float s = ELEM(xv, i);
            const float4* w = (const float4*)(W1t + (size_t)(k4 * 4 + i) * 64);
            float4 w0 = w[0], w1 = w[1], w2 = w[2], w3 = w[3];
            FMA4(a0, s, w0); FMA4(a1, s, w1);
            FMA4(a2, s, w2); FMA4(a3, s, w3);
        }
    }
    {
        const float4* bv = (const float4*)(b1 + t * 16);
        float4 b0 = bv[0], b1v = bv[1], b2v = bv[2], b3v = bv[3];
        float4 r0, r1, r2, r3;
        r0.x = fmaxf(a0.x + b0.x, 0.f);  r0.y = fmaxf(a0.y + b0.y, 0.f);
        r0.z = fmaxf(a0.z + b0.z, 0.f);  r0.w = fmaxf(a0.w + b0.w, 0.f);
        r1.x = fmaxf(a1.x + b1v.x, 0.f); r1.y = fmaxf(a1.y + b1v.y, 0.f);
        r1.z = fmaxf(a1.z + b1v.z, 0.f); r1.w = fmaxf(a1.w + b1v.w, 0.f);
        r2.x = fmaxf(a2.x + b2v.x, 0.f); r2.y = fmaxf(a2.y + b2v.y, 0.f);
        r2.z = fmaxf(a2.z + b2v.z, 0.f); r2.w = fmaxf(a2.w + b2v.w, 0.f);
        r3.x = fmaxf(a3.x + b3v.x, 0.f); r3.y = fmaxf(a3.y + b3v.y, 0.f);
        r3.z = fmaxf(a3.z + b3v.z, 0.f); r3.w = fmaxf(a3.w + b3v.w, 0.f);
        float4* d = (float4*)&h1s[ln][t * 16];
        d[0] = r0; d[1] = r1; d[2] = r2; d[3] = r3;
    }
    __syncthreads();

    // ---- L2: h slice = (h1@W2) + b2 ----
    a0 = make_float4(0.f, 0.f, 0.f, 0.f); a1 = a0; a2 = a0; a3 = a0;
    const float* W2t = W2 + t * 16;
    #pragma unroll 1
    for (int k4 = 0; k4 < 16; ++k4) {
        float4 hv = *(const float4*)&h1s[ln][k4 * 4];
        #pragma unroll
        for (int i = 0; i < 4; ++i) {
            float s = ELEM(hv, i);
            const float4* w = (const float4*)(W2t + (size_t)(k4 * 4 + i) * 64);
            float4 w0 = w[0], w1 = w[1], w2 = w[2], w3 = w[3];
            FMA4(a0, s, w0); FMA4(a1, s, w1);
            FMA4(a2, s, w2); FMA4(a3, s, w3);
        }
    }
    {
        const float4* bv = (const float4*)(b2 + t * 16);
        float4 b0 = bv[0], b1v = bv[1], b2v = bv[2], b3v = bv[3];
        float4 r0, r1, r2, r3;
        r0.x = a0.x + b0.x;  r0.y = a0.y + b0.y;  r0.z = a0.z + b0.z;  r0.w = a0.w + b0.w;
        r1.x = a1.x + b1v.x; r1.y = a1.y + b1v.y; r1.z = a1.z + b1v.z; r1.w = a1.w + b1v.w;
        r2.x = a2.x + b2v.x; r2.y = a2.y + b2v.y; r2.z = a2.z + b2v.z; r2.w = a2.w + b2v.w;
        r3.x = a3.x + b3v.x; r3.y = a3.y + b3v.y; r3.z = a3.z + b3v.z; r3.w = a3.w + b3v.w;
        float4* d = (float4*)&hs[ln][t * 16];
        d[0] = r0; d[1] = r1; d[2] = r2; d[3] = r3;
        if (n < N) {
            float4* g = (float4*)(Hout + (size_t)n * 64 + t * 16);
            g[0] = r0; g[1] = r1; g[2] = r2; g[3] = r3;
        }
    }
    __syncthreads();

    // ---- L3 row-half partial: A slice = h @ W3[0:64], no bias ----
    a0 = make_float4(0.f, 0.f, 0.f, 0.f); a1 = a0; a2 = a0; a3 = a0;
    const float* W3t = W3 + t * 16;
    #pragma unroll 1
    for (int k4 = 0; k4 < 16; ++k4) {
        float4 hv = *(const float4*)&hs[ln][k4 * 4];
        #pragma unroll
        for (int i = 0; i < 4; ++i) {
            float s = ELEM(hv, i);
            const float4* w = (const float4*)(W3t + (size_t)(k4 * 4 + i) * 64);
            float4 w0 = w[0], w1 = w[1], w2 = w[2], w3 = w[3];
            FMA4(a0, s, w0); FMA4(a1, s, w1);
            FMA4(a2, s, w2); FMA4(a3, s, w3);
        }
    }
    if (n < N) {
        float4* g = (float4*)(Aout + (size_t)n * 64 + t * 16);
        g[0] = a0; g[1] = a1; g[2] = a2; g[3] = a3;
    }
}

// Per edge: hid chain continues from A[row] with h[col] over W3 rows 64..127
// ascending (bit-identical to np's concat-gemm chain), +b3, relu, logits +b4,
// first-occurrence argmax, fp32 softmax. hid resident; hc STREAMED one
// float4 ahead (only ~8 extra VGPRs, loads hidden under 256 FMAs/iter).
__global__ __launch_bounds__(256, 4) void edge_kernel(
    const int* __restrict__ ei,
    const float* __restrict__ H, const float* __restrict__ A,
    const float* __restrict__ W3, const float* __restrict__ b3,
    const float* __restrict__ W4, const float* __restrict__ b4,
    float* __restrict__ out_type, float* __restrict__ out_probs, int E)
{
    int e = blockIdx.x * 256 + threadIdx.x;
    if (e >= E) return;

    int r = ei[e];
    int c = ei[E + e];

    const float4* Ar = (const float4*)(A + (size_t)r * 64);
    const float4* Hc = (const float4*)(H + (size_t)c * 64);

    float4 hid[16];
    #pragma unroll
    for (int i = 0; i < 16; ++i) hid[i] = Ar[i];

    const float* W3b = W3 + 64 * 64;
    float4 hcv = Hc[0];
    #pragma unroll 1
    for (int k4 = 0; k4 < 16; ++k4) {
        float4 hcn = Hc[(k4 + 1) & 15];   // prefetch next (wraps to [0], harmless)
        #pragma unroll
        for (int i = 0; i < 4; ++i) {
            float s = ELEM(hcv, i);
            const float* w = W3b + (size_t)(k4 * 4 + i) * 64;
            #pragma unroll
            for (int j = 0; j < 16; ++j) {
                float4 wv = *(const float4*)(w + 4 * j);
                FMA4(hid[j], s, wv);
            }
        }
        hcv = hcn;
    }
    #pragma unroll
    for (int j = 0; j < 16; ++j) {
        hid[j].x = fmaxf(hid[j].x + b3[4 * j + 0], 0.f);
        hid[j].y = fmaxf(hid[j].y + b3[4 * j + 1], 0.f);
        hid[j].z = fmaxf(hid[j].z + b3[4 * j + 2], 0.f);
        hid[j].w = fmaxf(hid[j].w + b3[4 * j + 3], 0.f);
    }

    // logits = (hid @ W4) + b4, ascending k
    float lg[NUM_REL];
    #pragma unroll
    for (int j = 0; j < NUM_REL; ++j) lg[j] = 0.0f;
    #pragma unroll
    for (int k4 = 0; k4 < 16; ++k4) {
        #pragma unroll
        for (int i = 0; i < 4; ++i) {
            float s = ELEM(hid[k4], i);
            const float* w = W4 + (size_t)(k4 * 4 + i) * NUM_REL;
            #pragma unroll
            for (int j = 0; j < NUM_REL; ++j) lg[j] = fmaf(s, w[j], lg[j]);
        }
    }
    #pragma unroll
    for (int j = 0; j < NUM_REL; ++j) lg[j] += b4[j];

    // argmax, first occurrence
    int best = 0;
    float bm = lg[0];
    #pragma unroll
    for (int j = 1; j < NUM_REL; ++j)
        if (lg[j] > bm) { bm = lg[j]; best = j; }

    // softmax fp32
    float p[NUM_REL];
    float sum = 0.0f;
    #pragma unroll
    for (int j = 0; j < NUM_REL; ++j) {
        p[j] = expf(lg[j] - bm);
        sum += p[j];
    }
    float inv = 1.0f / sum;

    out_type[e] = (float)best;
    float* op = out_probs + (size_t)e * NUM_REL;
    #pragma unroll
    for (int j = 0; j < NUM_REL; ++j) op[j] = p[j] * inv;
}

extern "C" void kernel_launch(void* const* d_in, const int* in_sizes, int n_in,
                              void* d_out, int out_size, void* d_ws, size_t ws_size,
                              hipStream_t stream)
{
    const float* x  = (const float*)d_in[0];
    const int*   ei = (const int*)d_in[1];
    const float* W1 = (const float*)d_in[2];
    const float* b1 = (const float*)d_in[3];
    const float* W2 = (const float*)d_in[4];
    const float* b2 = (const float*)d_in[5];
    const float* W3 = (const float*)d_in[6];
    const float* b3 = (const float*)d_in[7];
    const float* W4 = (const float*)d_in[8];
    const float* b4 = (const float*)d_in[9];

    int N = in_sizes[0] / NODE_DIM;   // 100000
    int E = in_sizes[1] / 2;          // 1600000

    // ws: H [N*64] f32 | A [N*64] f32   (51.2 MB total)
    float* H = (float*)d_ws;
    float* A = H + (size_t)N * 64;

    int nb = (N + NPB - 1) / NPB;
    int eb = (E + 255) / 256;

    float* out_type  = (float*)d_out;
    float* out_probs = (float*)d_out + E;

    hipLaunchKernelGGL(node_kernel, dim3(nb), dim3(256), 0, stream,
                       x, W1, b1, W2, b2, W3, H, A, N);
    hipLaunchKernelGGL(edge_kernel, dim3(eb), dim3(256), 0, stream,
                       ei, H, A, W3, b3, W4, b4, out_type, out_probs, E);
}

// Round 9
// 582.538 us; speedup vs baseline: 1.5317x; 1.5317x over previous
//
#include <hip/hip_runtime.h>

#define NODE_DIM 256
#define HIDDEN 64
#define NUM_REL 10

#define FMA4(A, S, W) do { \
    (A).x = fmaf((S), (W).x, (A).x); \
    (A).y = fmaf((S), (W).y, (A).y); \
    (A).z = fmaf((S), (W).z, (A).z); \
    (A).w = fmaf((S), (W).w, (A).w); } while (0)

#define ELEM(V, I) ((I) == 0 ? (V).x : (I) == 1 ? (V).y : (I) == 2 ? (V).z : (V).w)

// Schedulable remat-blocker: NON-volatile asm — the compiler may reorder it
// freely (unlike round-7's asm volatile, which serialized), but cannot
// rematerialize the gather feeding it, so values stay register-resident.
#define KEEP4(v) asm("" : "+v"((v).x), "+v"((v).y), "+v"((v).z), "+v"((v).w))

// ---- node kernel: round-5 version verbatim (110 us; wave-uniform W rows ->
// s_load scalarization; thread-per-node). np/BLAS rounding order: acc=0,
// ascending-k fmaf chain, bias added AFTER as separate add, then relu.
//   h1 = relu((x@W1)+b1); h = (h1@W2)+b2 -> stored; A = h@W3[0:64] -> stored.
__global__ __launch_bounds__(256) void node_kernel(
    const float* __restrict__ x,
    const float* __restrict__ W1, const float* __restrict__ b1,
    const float* __restrict__ W2, const float* __restrict__ b2,
    const float* __restrict__ W3,
    float* __restrict__ Hout, float* __restrict__ Aout, int N)
{
    int n = blockIdx.x * 256 + threadIdx.x;
    if (n >= N) return;

    // ---- L1: h1 = relu((x@W1) + b1) ----
    float h1[64];
    #pragma unroll
    for (int j = 0; j < 64; ++j) h1[j] = 0.0f;

    const float4* xr = (const float4*)(x + (size_t)n * NODE_DIM);
    #pragma unroll 1
    for (int k4 = 0; k4 < NODE_DIM / 4; ++k4) {
        float4 xv = xr[k4];
        const float* w = W1 + (size_t)k4 * 4 * 64;
        #pragma unroll
        for (int j = 0; j < 64; ++j) h1[j] = fmaf(xv.x, w[j], h1[j]);
        #pragma unroll
        for (int j = 0; j < 64; ++j) h1[j] = fmaf(xv.y, w[64 + j], h1[j]);
        #pragma unroll
        for (int j = 0; j < 64; ++j) h1[j] = fmaf(xv.z, w[128 + j], h1[j]);
        #pragma unroll
        for (int j = 0; j < 64; ++j) h1[j] = fmaf(xv.w, w[192 + j], h1[j]);
    }
    #pragma unroll
    for (int j = 0; j < 64; ++j) h1[j] = fmaxf(h1[j] + b1[j], 0.0f);

    // ---- L2: h = (h1@W2) + b2 ----
    float h[64];
    #pragma unroll
    for (int c = 0; c < 4; ++c) {
        float acc[16];
        #pragma unroll
        for (int j = 0; j < 16; ++j) acc[j] = 0.0f;
        #pragma unroll
        for (int k = 0; k < 64; ++k) {
            const float* w = W2 + (size_t)k * 64 + c * 16;
            #pragma unroll
            for (int j = 0; j < 16; ++j) acc[j] = fmaf(h1[k], w[j], acc[j]);
        }
        #pragma unroll
        for (int j = 0; j < 16; ++j) h[c * 16 + j] = acc[j] + b2[c * 16 + j];
    }

    float4* hr = (float4*)(Hout + (size_t)n * 64);
    #pragma unroll
    for (int j4 = 0; j4 < 16; ++j4) {
        float4 v;
        v.x = h[4 * j4]; v.y = h[4 * j4 + 1];
        v.z = h[4 * j4 + 2]; v.w = h[4 * j4 + 3];
        hr[j4] = v;
    }

    // ---- L3 row-half partial: A = h @ W3[0:64], no bias ----
    float4* ar = (float4*)(Aout + (size_t)n * 64);
    #pragma unroll
    for (int c = 0; c < 4; ++c) {
        float acc[16];
        #pragma unroll
        for (int j = 0; j < 16; ++j) acc[j] = 0.0f;
        #pragma unroll
        for (int k = 0; k < 64; ++k) {
            const float* w = W3 + (size_t)k * 64 + c * 16;
            #pragma unroll
            for (int j = 0; j < 16; ++j) acc[j] = fmaf(h[k], w[j], acc[j]);
        }
        #pragma unroll
        for (int j4 = 0; j4 < 4; ++j4) {
            float4 v;
            v.x = acc[4 * j4]; v.y = acc[4 * j4 + 1];
            v.z = acc[4 * j4 + 2]; v.w = acc[4 * j4 + 3];
            ar[c * 4 + j4] = v;
        }
    }
}

// logits + argmax + softmax + store for one finished hid row.
__device__ __forceinline__ void logits_out(
    const float4 hid[16], const float* __restrict__ W4,
    const float* __restrict__ b4, int e,
    float* __restrict__ out_type, float* __restrict__ out_probs)
{
    float lg[NUM_REL];
    #pragma unroll
    for (int j = 0; j < NUM_REL; ++j) lg[j] = 0.0f;
    #pragma unroll
    for (int k4 = 0; k4 < 16; ++k4) {
        #pragma unroll
        for (int i = 0; i < 4; ++i) {
            float s = ELEM(hid[k4], i);
            const float* w = W4 + (size_t)(k4 * 4 + i) * NUM_REL;
            #pragma unroll
            for (int j = 0; j < NUM_REL; ++j) lg[j] = fmaf(s, w[j], lg[j]);
        }
    }
    #pragma unroll
    for (int j = 0; j < NUM_REL; ++j) lg[j] += b4[j];

    int best = 0;
    float bm = lg[0];
    #pragma unroll
    for (int j = 1; j < NUM_REL; ++j)
        if (lg[j] > bm) { bm = lg[j]; best = j; }

    float p[NUM_REL];
    float sum = 0.0f;
    #pragma unroll
    for (int j = 0; j < NUM_REL; ++j) {
        p[j] = expf(lg[j] - bm);
        sum += p[j];
    }
    float inv = 1.0f / sum;

    out_type[e] = (float)best;
    float* op = out_probs + (size_t)e * NUM_REL;
    #pragma unroll
    for (int j = 0; j < NUM_REL; ++j) op[j] = p[j] * inv;
}

// TWO edges per thread: one s_load batch of W3b feeds both FMA chains
// (amortizes SMEM-wait 2x), hid rows pinned resident via schedulable KEEP4,
// hc rows streamed one float4 ahead. Chain order per element unchanged ->
// bit-identical to np's concat-gemm.
__global__ __launch_bounds__(256, 2) void edge_kernel(
    const int* __restrict__ ei,
    const float* __restrict__ H, const float* __restrict__ A,
    const float* __restrict__ W3, const float* __restrict__ b3,
    const float* __restrict__ W4, const float* __restrict__ b4,
    float* __restrict__ out_type, float* __restrict__ out_probs, int E)
{
    int g = blockIdx.x * 256 + threadIdx.x;
    int npairs = (E + 1) >> 1;
    if (g >= npairs) return;

    int eA = 2 * g;
    int eB = 2 * g + 1;
    bool hasB = (eB < E);
    if (!hasB) eB = eA;

    int rA = ei[eA], cA = ei[E + eA];
    int rB = ei[eB], cB = ei[E + eB];

    const float4* ArA = (const float4*)(A + (size_t)rA * 64);
    const float4* ArB = (const float4*)(A + (size_t)rB * 64);
    const float4* HcA = (const float4*)(H + (size_t)cA * 64);
    const float4* HcB = (const float4*)(H + (size_t)cB * 64);

    float4 hidA[16], hidB[16];
    #pragma unroll
    for (int i = 0; i < 16; ++i) { hidA[i] = ArA[i]; hidB[i] = ArB[i]; }
    #pragma unroll
    for (int i = 0; i < 16; ++i) { KEEP4(hidA[i]); KEEP4(hidB[i]); }

    const float* W3b = W3 + 64 * 64;
    float4 hvA = HcA[0];
    float4 hvB = HcB[0];
    #pragma unroll 1
    for (int k4 = 0; k4 < 16; ++k4) {
        float4 hnA = HcA[(k4 + 1) & 15];   // prefetch next (wrap harmless)
        float4 hnB = HcB[(k4 + 1) & 15];
        #pragma unroll
        for (int i = 0; i < 4; ++i) {
            float sA = ELEM(hvA, i);
            float sB = ELEM(hvB, i);
            const float* w = W3b + (size_t)(k4 * 4 + i) * 64;
            #pragma unroll
            for (int j = 0; j < 16; ++j) {
                float4 wv = *(const float4*)(w + 4 * j);
                FMA4(hidA[j], sA, wv);
                FMA4(hidB[j], sB, wv);
            }
        }
        hvA = hnA;
        hvB = hnB;
    }

    #pragma unroll
    for (int j = 0; j < 16; ++j) {
        float4 bv = *(const float4*)(b3 + 4 * j);
        hidA[j].x = fmaxf(hidA[j].x + bv.x, 0.f);
        hidA[j].y = fmaxf(hidA[j].y + bv.y, 0.f);
        hidA[j].z = fmaxf(hidA[j].z + bv.z, 0.f);
        hidA[j].w = fmaxf(hidA[j].w + bv.w, 0.f);
        hidB[j].x = fmaxf(hidB[j].x + bv.x, 0.f);
        hidB[j].y = fmaxf(hidB[j].y + bv.y, 0.f);
        hidB[j].z = fmaxf(hidB[j].z + bv.z, 0.f);
        hidB[j].w = fmaxf(hidB[j].w + bv.w, 0.f);
    }

    logits_out(hidA, W4, b4, eA, out_type, out_probs);
    if (hasB) logits_out(hidB, W4, b4, eB, out_type, out_probs);
}

extern "C" void kernel_launch(void* const* d_in, const int* in_sizes, int n_in,
                              void* d_out, int out_size, void* d_ws, size_t ws_size,
                              hipStream_t stream)
{
    const float* x  = (const float*)d_in[0];
    const int*   ei = (const int*)d_in[1];
    const float* W1 = (const float*)d_in[2];
    const float* b1 = (const float*)d_in[3];
    const float* W2 = (const float*)d_in[4];
    const float* b2 = (const float*)d_in[5];
    const float* W3 = (const float*)d_in[6];
    const float* b3 = (const float*)d_in[7];
    const float* W4 = (const float*)d_in[8];
    const float* b4 = (const float*)d_in[9];

    int N = in_sizes[0] / NODE_DIM;   // 100000
    int E = in_sizes[1] / 2;          // 1600000

    // ws: H [N*64] f32 | A [N*64] f32   (51.2 MB total)
    float* H = (float*)d_ws;
    float* A = H + (size_t)N * 64;

    int nb = (N + 255) / 256;
    int npairs = (E + 1) >> 1;
    int eb = (npairs + 255) / 256;

    float* out_type  = (float*)d_out;
    float* out_probs = (float*)d_out + E;

    hipLaunchKernelGGL(node_kernel, dim3(nb), dim3(256), 0, stream,
                       x, W1, b1, W2, b2, W3, H, A, N);
    hipLaunchKernelGGL(edge_kernel, dim3(eb), dim3(256), 0, stream,
                       ei, H, A, W3, b3, W4, b4, out_type, out_probs, E);
}